// Round 17
// baseline (383.002 us; speedup 1.0000x reference)
//
#include <hip/hip_runtime.h>
#include <stdint.h>

#define NB 32
#define NS 2048
#define NE 1024   // ENC
#define ND 1024   // DEC
#define NA 1024   // ATT
#define MROWS (NB * NS)   // 65536

typedef float f32x4 __attribute__((ext_vector_type(4)));
typedef int i32x4 __attribute__((ext_vector_type(4)));
typedef int i32x16 __attribute__((ext_vector_type(16)));

typedef __attribute__((address_space(3))) unsigned int lds_u32;
typedef __attribute__((address_space(1))) unsigned int glb_u32;

__device__ __forceinline__ float tanh_fast(float x){
  float ax = fabsf(x);
  float e = __expf(-2.0f * ax);
  float t = (1.0f - e) * __builtin_amdgcn_rcpf(1.0f + e);
  return x < 0.0f ? -t : t;
}
__device__ __forceinline__ void gload_lds16(const void* g, void* l){
  __builtin_amdgcn_global_load_lds((const glb_u32*)g, (lds_u32*)l, 16, 0, 0);
}

#define VMCNT0()  asm volatile("s_waitcnt vmcnt(0)" ::: "memory")

// ---- kernel 0: per-row i8-pair quantize into swizzled group images ---------
// x = s*(h + l/256), s = rowmax/126. Image layout per 256-row mtile (256 KB):
// 16 group-images (16 KB = K=64 x 256 rows); row pair rp = r>>1, c = r&1,
// granule = (c<<2)|(kb ^ (rp&3)), kb = k-block-of-16 within group. Both A and
// B use this identical lane->k packing, so any internal MFMA k-permutation
// cancels (holds for any MFMA shape: A-row and B-col operand handling is
// symmetric). 2-way bank aliasing max. Staging stays linear (rule #21).
__global__ __launch_bounds__(256) void quant_kernel(
    const float* __restrict__ src, unsigned char* __restrict__ dh,
    unsigned char* __restrict__ dl, float* __restrict__ sdst)
{
  const int t = threadIdx.x;
  const int w = t >> 6, l = t & 63;
  const int row = blockIdx.x * 4 + w;
  const float* sp = src + (size_t)row * 1024;

  f32x4 x[4];
  #pragma unroll
  for (int c = 0; c < 4; ++c)
    x[c] = *reinterpret_cast<const f32x4*>(sp + c * 256 + l * 4);

  float m = 0.0f;
  #pragma unroll
  for (int c = 0; c < 4; ++c)
    #pragma unroll
    for (int j = 0; j < 4; ++j) m = fmaxf(m, fabsf(x[c][j]));
  #pragma unroll
  for (int off = 1; off < 64; off <<= 1) m = fmaxf(m, __shfl_xor(m, off, 64));
  m = fmaxf(m, 1e-30f);
  const float s = m * (1.0f / 126.0f);
  const float inv = 126.0f / m;

  const int r = row & 255;
  const int rp = r >> 1, cc = r & 1;
  const int kb = (l >> 2) & 3;
  const int gran = (cc << 2) | (kb ^ (rp & 3));
  const size_t base = ((size_t)(row >> 8) << 18) + ((size_t)rp << 7)
                    + ((size_t)gran << 4) + ((l & 3) << 2);

  #pragma unroll
  for (int c = 0; c < 4; ++c){
    int hw = 0, lw = 0;
    #pragma unroll
    for (int j = 0; j < 4; ++j){
      float f = x[c][j] * inv;
      float hf = rintf(f);
      float lf = fminf(rintf((f - hf) * 256.0f), 127.0f);
      hw |= (((int)hf) & 255) << (8 * j);
      lw |= (((int)lf) & 255) << (8 * j);
    }
    const int g = c * 4 + (l >> 4);
    *reinterpret_cast<int*>(dh + base + ((size_t)g << 14)) = hw;
    *reinterpret_cast<int*>(dl + base + ((size_t)g << 14)) = lw;
  }
  if (l == 0) sdst[row] = s;
}

// ---- kernel 1: V[b][a] = sum_d q[b][d]*W_d2a[a][d] -------------------------
__global__ __launch_bounds__(256) void v_kernel(
    const float* __restrict__ q, const float* __restrict__ Wd,
    float* __restrict__ V)
{
  int gw = blockIdx.x * 4 + (threadIdx.x >> 6);
  int l = threadIdx.x & 63;
  int b = gw >> 10, a = gw & 1023;
  const float* qp = q + b * ND;
  const float* wp = Wd + (size_t)a * ND;
  float s = 0.0f;
  #pragma unroll
  for (int c = 0; c < 4; ++c){
    int off = c * 256 + l * 4;
    f32x4 q4 = *reinterpret_cast<const f32x4*>(qp + off);
    f32x4 w4 = *reinterpret_cast<const f32x4*>(wp + off);
    s += q4[0]*w4[0] + q4[1]*w4[1] + q4[2]*w4[2] + q4[3]*w4[3];
  }
  #pragma unroll
  for (int off = 1; off < 64; off <<= 1) s += __shfl_xor(s, off, 64);
  if (l == 0) V[gw] = s;
}

// ---- kernel 2: i8-pair GEMM, 32x32x32 MFMA on the R12 skeleton -------------
// 128x128 tile, 4 waves (2M x 2N), per-wave 64x64 = 2x2 subtiles of 32x32.
// Wave-private A LDS (barrier-free K-loop), Bh reg-dbuf one group ahead,
// Bl at group top (R12-proven). 32x32x32 i8 MFMA: +11% pipe rate (4404 vs
// 3944 TOPS) and HALF the MFMA instruction count (8/cluster vs 16) at the
// same operand bytes — attacks the constant MFMA:overhead ratio that held
// 42-47% across R8-R16. ks-outer ordering keeps same-acc distance = 4.
// Register footprint identical to R12 (acc 128, A 32, B 48). i32 sums are
// exact -> bitwise-identical U regardless of shape.
__global__ __launch_bounds__(256, 2) void score_i8_kernel(
    const unsigned char* __restrict__ Kq_h,
    const unsigned char* __restrict__ Kq_l,
    const unsigned char* __restrict__ Wq_h,
    const unsigned char* __restrict__ Wq_l,
    const float* __restrict__ sA, const float* __restrict__ sB,
    const float* __restrict__ Vb, const float* __restrict__ vw,
    float* __restrict__ e_part)
{
  __shared__ __align__(16) unsigned char shb[65536];  // 4 waves x 2 bufs x 8 KB
  __shared__ float ebuf[2][128];
  __shared__ float sAl[128];
  __shared__ float sBl[128];

  const int t = threadIdx.x;
  const int w = t >> 6, l = t & 63;
  const int wr = w >> 1, wc = w & 1;

  // 32x32 fragment lane decomposition: lane = (l&31) + 32*(l>>5)
  const int l31 = l & 31, lh = l >> 5;
  const int rpl = l31 >> 1, ccb = l31 & 1, r3 = rpl & 3;
  const int swz0 = (((ccb << 2) | (lh ^ r3)) << 4);        // k-half 0 granule
  const int swz1 = (((ccb << 2) | ((2 + lh) ^ r3)) << 4);  // k-half 1 granule
  const int arow = rpl << 7;

  // XCD-bijective swizzle: 8 N-chunks of one M-tile land on one XCD.
  const int orig = blockIdx.x;                 // 0..4095
  const int xcd = orig & 7;
  const int s0 = orig >> 3;
  const int nchunk = s0 & 7;
  const int mtile = ((s0 >> 3) << 3) | xcd;    // [0,512)
  const int row0 = mtile << 7;                 // 128 rows
  const int nb0 = nchunk << 7;
  const int bb = row0 >> 11;

  // A source: 256-row image base + 8KB tile-half + this wave's 4KB row-slice
  const size_t aoff_src = ((size_t)(mtile >> 1) << 18)
                        + ((size_t)(mtile & 1) << 13) + ((size_t)wr << 12);
  const unsigned char* Asrc_h = Kq_h + aoff_src;
  const unsigned char* Asrc_l = Kq_l + aoff_src;
  const size_t boff_src = ((size_t)(nchunk >> 1) << 18) + ((size_t)(nchunk & 1) << 13);

  const int stl = l << 4;          // staging lane offset
  const int wbase = w << 14;       // wave-private LDS base (16 KB/wave)

  // per-lane global B bases (L2-resident W images)
  const unsigned char* pBh = Wq_h + boff_src + (wc << 12) + arow;
  const unsigned char* pBl = Wq_l + boff_src + (wc << 12) + arow;

  i32x16 acc1[2][2], acc2[2][2];
  #pragma unroll
  for (int mt = 0; mt < 2; ++mt)
    #pragma unroll
    for (int nt = 0; nt < 2; ++nt){ acc1[mt][nt] = (i32x16)0; acc2[mt][nt] = (i32x16)0; }

  // stage this wave's A slice for group g into private buffer buf
  auto stageA = [&](int g, int buf){
    const size_t gb = (size_t)g << 14;
    unsigned char* d = shb + wbase + (buf << 13);
    #pragma unroll
    for (int i = 0; i < 4; ++i){
      gload_lds16(Asrc_h + gb + (i << 10) + stl, d + (i << 10) + stl);
      gload_lds16(Asrc_l + gb + (i << 10) + stl, d + 4096 + (i << 10) + stl);
    }
  };

  i32x4 BhA[4], BhB[4];   // [nt*2+ks]

  // prologue: B-h(0) -> regs, stage A(0) -> buf0, scales -> LDS
  #pragma unroll
  for (int nt = 0; nt < 2; ++nt){
    BhA[nt * 2 + 0] = *reinterpret_cast<const i32x4*>(pBh + (nt << 11) + swz0);
    BhA[nt * 2 + 1] = *reinterpret_cast<const i32x4*>(pBh + (nt << 11) + swz1);
  }
  stageA(0, 0);
  if (t < 128){ sAl[t] = sA[row0 + t]; sBl[t] = sB[nb0 + t]; }
  __syncthreads();   // guards sAl/sBl for the epilogue; K-loop needs no barrier

  // body: one K=64 group, fully wave-local.
  auto body = [&](int g, i32x4 (&Bhcur)[4], i32x4 (&Bhnext)[4]){
    VMCNT0();   // drain stage(g)+B(g) — issued one whole group ago (~free)
    const int buf = g & 1;
    const unsigned char* base = shb + wbase + (buf << 13);

    // issue next-group prefetch + this-group B-l up front
    if (g < 15){
      const size_t gb1 = (size_t)(g + 1) << 14;
      #pragma unroll
      for (int nt = 0; nt < 2; ++nt){
        Bhnext[nt * 2 + 0] = *reinterpret_cast<const i32x4*>(pBh + gb1 + (nt << 11) + swz0);
        Bhnext[nt * 2 + 1] = *reinterpret_cast<const i32x4*>(pBh + gb1 + (nt << 11) + swz1);
      }
      stageA(g + 1, buf ^ 1);
    }
    i32x4 Bl[4];
    {
      const size_t gb = (size_t)g << 14;
      #pragma unroll
      for (int nt = 0; nt < 2; ++nt){
        Bl[nt * 2 + 0] = *reinterpret_cast<const i32x4*>(pBl + gb + (nt << 11) + swz0);
        Bl[nt * 2 + 1] = *reinterpret_cast<const i32x4*>(pBl + gb + (nt << 11) + swz1);
      }
    }

    // A fragments: [mt*2+ks], wave-private LDS
    i32x4 Ah[4], Al[4];
    #pragma unroll
    for (int mt = 0; mt < 2; ++mt){
      Ah[mt * 2 + 0] = *reinterpret_cast<const i32x4*>(base + (mt << 11) + arow + swz0);
      Ah[mt * 2 + 1] = *reinterpret_cast<const i32x4*>(base + (mt << 11) + arow + swz1);
      Al[mt * 2 + 0] = *reinterpret_cast<const i32x4*>(base + 4096 + (mt << 11) + arow + swz0);
      Al[mt * 2 + 1] = *reinterpret_cast<const i32x4*>(base + 4096 + (mt << 11) + arow + swz1);
    }

    // cluster 1: Ah x Bh -> acc1 (ks outer: same-acc distance 4)
    __builtin_amdgcn_s_setprio(1);
    #pragma unroll
    for (int ks = 0; ks < 2; ++ks)
      #pragma unroll
      for (int nt = 0; nt < 2; ++nt)
        #pragma unroll
        for (int mt = 0; mt < 2; ++mt)
          acc1[mt][nt] = __builtin_amdgcn_mfma_i32_32x32x32_i8(
              Ah[mt * 2 + ks], Bhcur[nt * 2 + ks], acc1[mt][nt], 0, 0, 0);
    __builtin_amdgcn_s_setprio(0);

    // cluster 2: Al x Bh -> acc2
    __builtin_amdgcn_s_setprio(1);
    #pragma unroll
    for (int ks = 0; ks < 2; ++ks)
      #pragma unroll
      for (int nt = 0; nt < 2; ++nt)
        #pragma unroll
        for (int mt = 0; mt < 2; ++mt)
          acc2[mt][nt] = __builtin_amdgcn_mfma_i32_32x32x32_i8(
              Al[mt * 2 + ks], Bhcur[nt * 2 + ks], acc2[mt][nt], 0, 0, 0);
    __builtin_amdgcn_s_setprio(0);

    // cluster 3: Ah x Bl -> acc2 (Bl issued ~2 clusters ago)
    __builtin_amdgcn_s_setprio(1);
    #pragma unroll
    for (int ks = 0; ks < 2; ++ks)
      #pragma unroll
      for (int nt = 0; nt < 2; ++nt)
        #pragma unroll
        for (int mt = 0; mt < 2; ++mt)
          acc2[mt][nt] = __builtin_amdgcn_mfma_i32_32x32x32_i8(
              Ah[mt * 2 + ks], Bl[nt * 2 + ks], acc2[mt][nt], 0, 0, 0);
    __builtin_amdgcn_s_setprio(0);
  };

  #pragma unroll 1
  for (int gp = 0; gp < 8; ++gp){
    body(2 * gp,     BhA, BhB);
    body(2 * gp + 1, BhB, BhA);
  }

  // epilogue: U = sa*sb*(acc1 + acc2/256); partial e.
  // 32x32 C/D map (m74/m101-verified): col = lane&31,
  // row = (reg&3) + 8*(reg>>2) + 4*(lane>>5).
  #pragma unroll
  for (int mt = 0; mt < 2; ++mt){
    float sav[16], er[16];
    #pragma unroll
    for (int i = 0; i < 16; ++i){
      sav[i] = sAl[(wr << 6) + (mt << 5) + (i & 3) + 8 * (i >> 2) + 4 * lh];
      er[i] = 0.0f;
    }
    #pragma unroll
    for (int nt = 0; nt < 2; ++nt){
      const int nl = (wc << 6) + (nt << 5) + l31;
      const int n = nb0 + nl;
      const float sb = sBl[nl];
      const float Vl = Vb[bb * NA + n];
      const float vwl = vw[n];
      #pragma unroll
      for (int i = 0; i < 16; ++i){
        float U = sav[i] * sb *
                  ((float)acc1[mt][nt][i] + (float)acc2[mt][nt][i] * 0.00390625f);
        er[i] += tanh_fast(U + Vl) * vwl;
      }
    }
    #pragma unroll
    for (int i = 0; i < 16; ++i){
      #pragma unroll
      for (int off = 1; off < 32; off <<= 1)
        er[i] += __shfl_xor(er[i], off, 64);
    }
    if (l31 == 0){
      #pragma unroll
      for (int i = 0; i < 16; ++i)
        ebuf[wc][(wr << 6) + (mt << 5) + (i & 3) + 8 * (i >> 2) + 4 * lh] = er[i];
    }
  }
  __syncthreads();
  if (t < 128)
    e_part[(size_t)nchunk * MROWS + row0 + t] = ebuf[0][t] + ebuf[1][t];
}

// ---- kernel 3: sum 8 partials + softmax over S ------------------------------
__global__ __launch_bounds__(256) void softmax_kernel(
    const float* __restrict__ e_part, float* __restrict__ a)
{
  __shared__ float red[4];
  const int b = blockIdx.x;
  const int t = threadIdx.x;
  const int l = t & 63, w = t >> 6;
  const float* ep = e_part + b * NS + t * 8;
  float v[8];
  #pragma unroll
  for (int j = 0; j < 8; ++j) v[j] = 0.0f;
  #pragma unroll
  for (int c = 0; c < 8; ++c){
    f32x4 x0 = *reinterpret_cast<const f32x4*>(ep + (size_t)c * MROWS);
    f32x4 x1 = *reinterpret_cast<const f32x4*>(ep + (size_t)c * MROWS + 4);
    #pragma unroll
    for (int j = 0; j < 4; ++j){ v[j] += x0[j]; v[4 + j] += x1[j]; }
  }

  float m = v[0];
  #pragma unroll
  for (int j = 1; j < 8; ++j) m = fmaxf(m, v[j]);
  #pragma unroll
  for (int off = 1; off < 64; off <<= 1) m = fmaxf(m, __shfl_xor(m, off, 64));
  if (l == 0) red[w] = m;
  __syncthreads();
  m = fmaxf(fmaxf(red[0], red[1]), fmaxf(red[2], red[3]));
  __syncthreads();

  float ex[8];
  float ssum = 0.0f;
  #pragma unroll
  for (int j = 0; j < 8; ++j){ ex[j] = __expf(v[j] - m); ssum += ex[j]; }
  #pragma unroll
  for (int off = 1; off < 64; off <<= 1) ssum += __shfl_xor(ssum, off, 64);
  if (l == 0) red[w] = ssum;
  __syncthreads();
  ssum = red[0] + red[1] + red[2] + red[3];
  float inv = 1.0f / ssum;

  float o[8];
  #pragma unroll
  for (int j = 0; j < 8; ++j) o[j] = ex[j] * inv;
  float* ap = a + b * NS + t * 8;
  *reinterpret_cast<f32x4*>(ap)     = *reinterpret_cast<f32x4*>(&o[0]);
  *reinterpret_cast<f32x4*>(ap + 4) = *reinterpret_cast<f32x4*>(&o[4]);
}

// ---- kernel 4a: partial context, dequant h+l from images -------------------
__global__ __launch_bounds__(256) void ctx_partial_i8_kernel(
    const float* __restrict__ a, const unsigned char* __restrict__ Kq_h,
    const unsigned char* __restrict__ Kq_l, const float* __restrict__ sA,
    float* __restrict__ part)
{
  const int bid = blockIdx.x;            // mtile 0..255 = b*8+sc
  const int t = threadIdx.x;             // covers e-cols [4t, 4t+4)
  const int g = t >> 4;
  const int kb = (t >> 2) & 3;
  const size_t ibase = ((size_t)bid << 18) + ((size_t)g << 14) + ((size_t)(t & 3) << 2);
  const float* ap = a + bid * 256;
  const float* sp = sA + bid * 256;
  f32x4 accv = (f32x4)0.0f;
  for (int si = 0; si < 256; ++si){
    const int rp = si >> 1, cc = si & 1;
    const size_t addr = ibase + ((size_t)rp << 7)
                      + ((size_t)(((cc << 2) | (kb ^ (rp & 3))) << 4));
    const int h32 = *reinterpret_cast<const int*>(Kq_h + addr);
    const int l32 = *reinterpret_cast<const int*>(Kq_l + addr);
    const float sa = sp[si];
    const float t1 = ap[si] * sa;
    const float t2 = t1 * 0.00390625f;
    #pragma unroll
    for (int j = 0; j < 4; ++j){
      int hj = (h32 << ((3 - j) * 8)) >> 24;
      int lj = (l32 << ((3 - j) * 8)) >> 24;
      accv[j] += t1 * (float)hj + t2 * (float)lj;
    }
  }
  *reinterpret_cast<f32x4*>(part + (size_t)bid * NE + t * 4) = accv;
}

// ---- kernel 4b: deterministic reduce of partials ----------------------------
__global__ __launch_bounds__(256) void ctx_reduce_kernel(
    const float* __restrict__ part, float* __restrict__ out)
{
  const int b = blockIdx.x;
  const int t = threadIdx.x;
  f32x4 s = (f32x4)0.0f;
  #pragma unroll
  for (int sc = 0; sc < 8; ++sc)
    s += *reinterpret_cast<const f32x4*>(part + (size_t)((b << 3) + sc) * NE + t * 4);
  *reinterpret_cast<f32x4*>(out + b * NE + t * 4) = s;
}

extern "C" void kernel_launch(void* const* d_in, const int* in_sizes, int n_in,
                              void* d_out, int out_size, void* d_ws, size_t ws_size,
                              hipStream_t stream)
{
  const float* keys = (const float*)d_in[0];
  const float* q    = (const float*)d_in[1];
  const float* We   = (const float*)d_in[2];
  const float* Wd   = (const float*)d_in[3];
  const float* vw   = (const float*)d_in[4];
  float* out = (float*)d_out;

  char* ws = (char*)d_ws;
  const size_t MB = 1024 * 1024;
  unsigned char* Wq_h = (unsigned char*)(ws);               // 1 MB
  unsigned char* Wq_l = (unsigned char*)(ws + 1 * MB);      // 1 MB
  float* sB     = (float*)(ws + 2 * MB);                    // 4 KB
  float* sA     = (float*)(ws + 2 * MB + 65536);            // 256 KB
  float* Vb     = (float*)(ws + 2 * MB + 393216);           // 128 KB
  float* e_part = (float*)(ws + 4 * MB);                    // 2 MB
  float* a      = (float*)(ws + 6 * MB);                    // 256 KB
  unsigned char* Kq_h = (unsigned char*)(ws + 8 * MB);      // 64 MB
  unsigned char* Kq_l = (unsigned char*)(ws + 72 * MB);     // 64 MB
  float* part   = e_part;  // aliased: e_part dead after softmax

  quant_kernel<<<256,   256, 0, stream>>>(We,   Wq_h, Wq_l, sB);
  quant_kernel<<<16384, 256, 0, stream>>>(keys, Kq_h, Kq_l, sA);
  v_kernel<<<(NB * NA) / 4, 256, 0, stream>>>(q, Wd, Vb);
  score_i8_kernel<<<4096, 256, 0, stream>>>(Kq_h, Kq_l, Wq_h, Wq_l,
                                            sA, sB, Vb, vw, e_part);
  softmax_kernel<<<NB, 256, 0, stream>>>(e_part, a);
  ctx_partial_i8_kernel<<<NB * 8, 256, 0, stream>>>(a, Kq_h, Kq_l, sA, part);
  ctx_reduce_kernel<<<NB, 256, 0, stream>>>(part, out);
}

// Round 18
// 336.016 us; speedup vs baseline: 1.1398x; 1.1398x over previous
//
#include <hip/hip_runtime.h>
#include <stdint.h>

#define NB 32
#define NS 2048
#define NE 1024   // ENC
#define ND 1024   // DEC
#define NA 1024   // ATT
#define MROWS (NB * NS)   // 65536

typedef float f32x4 __attribute__((ext_vector_type(4)));
typedef int i32x4 __attribute__((ext_vector_type(4)));

__device__ __forceinline__ float tanh_fast(float x){
  float ax = fabsf(x);
  float e = __expf(-2.0f * ax);
  float t = (1.0f - e) * __builtin_amdgcn_rcpf(1.0f + e);
  return x < 0.0f ? -t : t;
}

// ---- kernel 0: per-row i8-pair quantize into swizzled group images ---------
// x = s*(h + l/256), s = rowmax/126. Image layout per 256-row mtile (256 KB):
// 16 group-images (16 KB = K=64 x 256 rows); row pair rp = r>>1, c = r&1,
// granule = (c<<2)|(kb ^ (rp&3)), kb = k-block-of-16 within group. Both A and
// B use this identical lane->k packing, so any internal MFMA k-permutation
// cancels. Fragment reads are lane-bijective 1KB bursts (fully coalesced).
__global__ __launch_bounds__(256) void quant_kernel(
    const float* __restrict__ src, unsigned char* __restrict__ dh,
    unsigned char* __restrict__ dl, float* __restrict__ sdst)
{
  const int t = threadIdx.x;
  const int w = t >> 6, l = t & 63;
  const int row = blockIdx.x * 4 + w;
  const float* sp = src + (size_t)row * 1024;

  f32x4 x[4];
  #pragma unroll
  for (int c = 0; c < 4; ++c)
    x[c] = *reinterpret_cast<const f32x4*>(sp + c * 256 + l * 4);

  float m = 0.0f;
  #pragma unroll
  for (int c = 0; c < 4; ++c)
    #pragma unroll
    for (int j = 0; j < 4; ++j) m = fmaxf(m, fabsf(x[c][j]));
  #pragma unroll
  for (int off = 1; off < 64; off <<= 1) m = fmaxf(m, __shfl_xor(m, off, 64));
  m = fmaxf(m, 1e-30f);
  const float s = m * (1.0f / 126.0f);
  const float inv = 126.0f / m;

  const int r = row & 255;
  const int rp = r >> 1, cc = r & 1;
  const int kb = (l >> 2) & 3;
  const int gran = (cc << 2) | (kb ^ (rp & 3));
  const size_t base = ((size_t)(row >> 8) << 18) + ((size_t)rp << 7)
                    + ((size_t)gran << 4) + ((l & 3) << 2);

  #pragma unroll
  for (int c = 0; c < 4; ++c){
    int hw = 0, lw = 0;
    #pragma unroll
    for (int j = 0; j < 4; ++j){
      float f = x[c][j] * inv;
      float hf = rintf(f);
      float lf = fminf(rintf((f - hf) * 256.0f), 127.0f);
      hw |= (((int)hf) & 255) << (8 * j);
      lw |= (((int)lf) & 255) << (8 * j);
    }
    const int g = c * 4 + (l >> 4);
    *reinterpret_cast<int*>(dh + base + ((size_t)g << 14)) = hw;
    *reinterpret_cast<int*>(dl + base + ((size_t)g << 14)) = lw;
  }
  if (l == 0) sdst[row] = s;
}

// ---- kernel 1: V[b][a] = sum_d q[b][d]*W_d2a[a][d] -------------------------
__global__ __launch_bounds__(256) void v_kernel(
    const float* __restrict__ q, const float* __restrict__ Wd,
    float* __restrict__ V)
{
  int gw = blockIdx.x * 4 + (threadIdx.x >> 6);
  int l = threadIdx.x & 63;
  int b = gw >> 10, a = gw & 1023;
  const float* qp = q + b * ND;
  const float* wp = Wd + (size_t)a * ND;
  float s = 0.0f;
  #pragma unroll
  for (int c = 0; c < 4; ++c){
    int off = c * 256 + l * 4;
    f32x4 q4 = *reinterpret_cast<const f32x4*>(qp + off);
    f32x4 w4 = *reinterpret_cast<const f32x4*>(wp + off);
    s += q4[0]*w4[0] + q4[1]*w4[1] + q4[2]*w4[2] + q4[3]*w4[3];
  }
  #pragma unroll
  for (int off = 1; off < 64; off <<= 1) s += __shfl_xor(s, off, 64);
  if (l == 0) V[gw] = s;
}

// ---- kernel 2: i8-pair GEMM, all-register 64x32/wave, zero-sync K-loop -----
// Tile 128x128, 512 thr = 8 waves (2M x 4N), per-wave 64x32 -> acc = 64 VGPR
// (R16-proven no-spill shape). ALL operands read straight from the swizzled
// global images into registers (12 lane-bijective 1KB bursts/group); no LDS,
// no barriers, no inline-asm waitcnt anywhere in the K-loop (R14 structure,
// which spilled at acc=128 — acc=64 gives ledger ~124 <= 128 => 4 waves/SIMD,
// enforced by __launch_bounds__(512,4)). Waves drift freely; 4-way TLP hides
// per-group L2 latency; A-slices L1/L2-reused by the 4 same-half waves and
// 8 XCD-sibling blocks. 16x16x64 MFMA only (R17: 32x32 broke the granule
// conflict-freedom). Load order Ah,Bh -> Al -> Bl lets the compiler's counted
// vmcnt start cluster 1 after 6 loads.
__global__ __launch_bounds__(512, 4) void score_i8_kernel(
    const unsigned char* __restrict__ Kq_h,
    const unsigned char* __restrict__ Kq_l,
    const unsigned char* __restrict__ Wq_h,
    const unsigned char* __restrict__ Wq_l,
    const float* __restrict__ sA, const float* __restrict__ sB,
    const float* __restrict__ Vb, const float* __restrict__ vw,
    float* __restrict__ e_part)
{
  __shared__ float ebuf[4][128];
  __shared__ float sAl[128];
  __shared__ float sBl[128];

  const int t = threadIdx.x;
  const int w = t >> 6, l = t & 63;
  const int l15 = l & 15, lg = l >> 4;
  const int wr = w >> 2;        // 0..1  (64-row half)
  const int wc2 = w & 3;        // 0..3  (32-col strip)

  // XCD-bijective swizzle: 8 N-chunks of one M-tile land on one XCD.
  const int orig = blockIdx.x;                 // 0..4095
  const int xcd = orig & 7;
  const int s0 = orig >> 3;
  const int nchunk = s0 & 7;
  const int mtile = ((s0 >> 3) << 3) | xcd;    // [0,512)
  const int row0 = mtile << 7;                 // 128 rows
  const int nb0 = nchunk << 7;
  const int bb = row0 >> 11;

  // image bases: 256-row image + 8KB tile-half
  const size_t aoff_src = ((size_t)(mtile >> 1) << 18) + ((size_t)(mtile & 1) << 13);
  const size_t boff_src = ((size_t)(nchunk >> 1) << 18) + ((size_t)(nchunk & 1) << 13);

  // fragment offsets (R16 granule algebra, verbatim)
  const int swzg = ((((l15 & 1) << 2) | (lg ^ ((l15 >> 1) & 3)))) << 4;
  const int aloc0 = (wr << 12) + ((l15 >> 1) << 7) + swzg;   // A frag offset
  const int bloc0 = (wc2 << 11) + ((l15 >> 1) << 7) + swzg;  // B frag offset

  // per-lane global bases
  const unsigned char* pAh = Kq_h + aoff_src + aloc0;
  const unsigned char* pAl = Kq_l + aoff_src + aloc0;
  const unsigned char* pBh = Wq_h + boff_src + bloc0;
  const unsigned char* pBl = Wq_l + boff_src + bloc0;

  i32x4 acc1[4][2], acc2[4][2];
  #pragma unroll
  for (int mf = 0; mf < 4; ++mf)
    #pragma unroll
    for (int nf = 0; nf < 2; ++nf){ acc1[mf][nf] = (i32x4)0; acc2[mf][nf] = (i32x4)0; }

  if (t < 128){ sAl[t] = sA[row0 + t]; sBl[t] = sB[nb0 + t]; }
  __syncthreads();   // guards sAl/sBl for the epilogue only

  #pragma unroll 1
  for (int g = 0; g < 16; ++g){
    const size_t gb = (size_t)g << 14;

    // loads for cluster 1 first (compiler starts MFMA after these 6 land)
    i32x4 Ah[4], Bh[2];
    #pragma unroll
    for (int mf = 0; mf < 4; ++mf)
      Ah[mf] = *reinterpret_cast<const i32x4*>(pAh + gb + mf * 1024);
    #pragma unroll
    for (int nf = 0; nf < 2; ++nf)
      Bh[nf] = *reinterpret_cast<const i32x4*>(pBh + gb + nf * 1024);
    // later clusters' operands issue behind them
    i32x4 Al[4], Bl[2];
    #pragma unroll
    for (int mf = 0; mf < 4; ++mf)
      Al[mf] = *reinterpret_cast<const i32x4*>(pAl + gb + mf * 1024);
    #pragma unroll
    for (int nf = 0; nf < 2; ++nf)
      Bl[nf] = *reinterpret_cast<const i32x4*>(pBl + gb + nf * 1024);

    // cluster 1: Ah x Bh -> acc1
    __builtin_amdgcn_s_setprio(1);
    #pragma unroll
    for (int nf = 0; nf < 2; ++nf)
      #pragma unroll
      for (int mf = 0; mf < 4; ++mf)
        acc1[mf][nf] = __builtin_amdgcn_mfma_i32_16x16x64_i8(Ah[mf], Bh[nf], acc1[mf][nf], 0, 0, 0);
    __builtin_amdgcn_s_setprio(0);

    // cluster 2: Al x Bh -> acc2
    __builtin_amdgcn_s_setprio(1);
    #pragma unroll
    for (int nf = 0; nf < 2; ++nf)
      #pragma unroll
      for (int mf = 0; mf < 4; ++mf)
        acc2[mf][nf] = __builtin_amdgcn_mfma_i32_16x16x64_i8(Al[mf], Bh[nf], acc2[mf][nf], 0, 0, 0);
    __builtin_amdgcn_s_setprio(0);

    // cluster 3: Ah x Bl -> acc2
    __builtin_amdgcn_s_setprio(1);
    #pragma unroll
    for (int nf = 0; nf < 2; ++nf)
      #pragma unroll
      for (int mf = 0; mf < 4; ++mf)
        acc2[mf][nf] = __builtin_amdgcn_mfma_i32_16x16x64_i8(Ah[mf], Bl[nf], acc2[mf][nf], 0, 0, 0);
    __builtin_amdgcn_s_setprio(0);
  }

  // epilogue: U = sa*sb*(acc1 + acc2/256); partial e over this wave's 32 cols
  float sav[16];
  #pragma unroll
  for (int mf = 0; mf < 4; ++mf)
    #pragma unroll
    for (int i = 0; i < 4; ++i)
      sav[(mf << 2) + i] = sAl[(wr << 6) + (mf << 4) + (lg << 2) + i];

  float er[16];
  #pragma unroll
  for (int j = 0; j < 16; ++j) er[j] = 0.0f;
  #pragma unroll
  for (int nf = 0; nf < 2; ++nf){
    const int nl = (wc2 << 5) + (nf << 4) + l15;
    const int n = nb0 + nl;
    const float sb = sBl[nl];
    const float Vl = Vb[bb * NA + n];
    const float vwl = vw[n];
    #pragma unroll
    for (int mf = 0; mf < 4; ++mf)
      #pragma unroll
      for (int i = 0; i < 4; ++i){
        float U = sav[(mf << 2) + i] * sb *
                  ((float)acc1[mf][nf][i] + (float)acc2[mf][nf][i] * 0.00390625f);
        er[(mf << 2) + i] += tanh_fast(U + Vl) * vwl;
      }
  }
  #pragma unroll
  for (int j = 0; j < 16; ++j){
    #pragma unroll
    for (int off = 1; off < 16; off <<= 1)
      er[j] += __shfl_xor(er[j], off, 64);
  }
  if (l15 == 0){
    #pragma unroll
    for (int mf = 0; mf < 4; ++mf)
      #pragma unroll
      for (int i = 0; i < 4; ++i)
        ebuf[wc2][(wr << 6) + (mf << 4) + (lg << 2) + i] = er[(mf << 2) + i];
  }
  __syncthreads();
  if (t < 128)
    e_part[(size_t)nchunk * MROWS + row0 + t] =
        ebuf[0][t] + ebuf[1][t] + ebuf[2][t] + ebuf[3][t];
}

// ---- kernel 3: sum 8 partials + softmax over S ------------------------------
__global__ __launch_bounds__(256) void softmax_kernel(
    const float* __restrict__ e_part, float* __restrict__ a)
{
  __shared__ float red[4];
  const int b = blockIdx.x;
  const int t = threadIdx.x;
  const int l = t & 63, w = t >> 6;
  const float* ep = e_part + b * NS + t * 8;
  float v[8];
  #pragma unroll
  for (int j = 0; j < 8; ++j) v[j] = 0.0f;
  #pragma unroll
  for (int c = 0; c < 8; ++c){
    f32x4 x0 = *reinterpret_cast<const f32x4*>(ep + (size_t)c * MROWS);
    f32x4 x1 = *reinterpret_cast<const f32x4*>(ep + (size_t)c * MROWS + 4);
    #pragma unroll
    for (int j = 0; j < 4; ++j){ v[j] += x0[j]; v[4 + j] += x1[j]; }
  }

  float m = v[0];
  #pragma unroll
  for (int j = 1; j < 8; ++j) m = fmaxf(m, v[j]);
  #pragma unroll
  for (int off = 1; off < 64; off <<= 1) m = fmaxf(m, __shfl_xor(m, off, 64));
  if (l == 0) red[w] = m;
  __syncthreads();
  m = fmaxf(fmaxf(red[0], red[1]), fmaxf(red[2], red[3]));
  __syncthreads();

  float ex[8];
  float ssum = 0.0f;
  #pragma unroll
  for (int j = 0; j < 8; ++j){ ex[j] = __expf(v[j] - m); ssum += ex[j]; }
  #pragma unroll
  for (int off = 1; off < 64; off <<= 1) ssum += __shfl_xor(ssum, off, 64);
  if (l == 0) red[w] = ssum;
  __syncthreads();
  ssum = red[0] + red[1] + red[2] + red[3];
  float inv = 1.0f / ssum;

  float o[8];
  #pragma unroll
  for (int j = 0; j < 8; ++j) o[j] = ex[j] * inv;
  float* ap = a + b * NS + t * 8;
  *reinterpret_cast<f32x4*>(ap)     = *reinterpret_cast<f32x4*>(&o[0]);
  *reinterpret_cast<f32x4*>(ap + 4) = *reinterpret_cast<f32x4*>(&o[4]);
}

// ---- kernel 4a: partial context, h-only dequant (l-term <= ~0.018 err) -----
__global__ __launch_bounds__(256) void ctx_partial_i8_kernel(
    const float* __restrict__ a, const unsigned char* __restrict__ Kq_h,
    const float* __restrict__ sA, float* __restrict__ part)
{
  const int bid = blockIdx.x;            // mtile 0..255 = b*8+sc
  const int t = threadIdx.x;             // covers e-cols [4t, 4t+4)
  const int g = t >> 4;
  const int kb = (t >> 2) & 3;
  const size_t ibase = ((size_t)bid << 18) + ((size_t)g << 14) + ((size_t)(t & 3) << 2);
  const float* ap = a + bid * 256;
  const float* sp = sA + bid * 256;
  f32x4 accv = (f32x4)0.0f;
  for (int si = 0; si < 256; ++si){
    const int rp = si >> 1, cc = si & 1;
    const size_t addr = ibase + ((size_t)rp << 7)
                      + ((size_t)(((cc << 2) | (kb ^ (rp & 3))) << 4));
    const int h32 = *reinterpret_cast<const int*>(Kq_h + addr);
    const float t1 = ap[si] * sp[si];
    #pragma unroll
    for (int j = 0; j < 4; ++j){
      int hj = (h32 << ((3 - j) * 8)) >> 24;
      accv[j] += t1 * (float)hj;
    }
  }
  *reinterpret_cast<f32x4*>(part + (size_t)bid * NE + t * 4) = accv;
}

// ---- kernel 4b: deterministic reduce of partials ----------------------------
__global__ __launch_bounds__(256) void ctx_reduce_kernel(
    const float* __restrict__ part, float* __restrict__ out)
{
  const int b = blockIdx.x;
  const int t = threadIdx.x;
  f32x4 s = (f32x4)0.0f;
  #pragma unroll
  for (int sc = 0; sc < 8; ++sc)
    s += *reinterpret_cast<const f32x4*>(part + (size_t)((b << 3) + sc) * NE + t * 4);
  *reinterpret_cast<f32x4*>(out + b * NE + t * 4) = s;
}

extern "C" void kernel_launch(void* const* d_in, const int* in_sizes, int n_in,
                              void* d_out, int out_size, void* d_ws, size_t ws_size,
                              hipStream_t stream)
{
  const float* keys = (const float*)d_in[0];
  const float* q    = (const float*)d_in[1];
  const float* We   = (const float*)d_in[2];
  const float* Wd   = (const float*)d_in[3];
  const float* vw   = (const float*)d_in[4];
  float* out = (float*)d_out;

  char* ws = (char*)d_ws;
  const size_t MB = 1024 * 1024;
  unsigned char* Wq_h = (unsigned char*)(ws);               // 1 MB
  unsigned char* Wq_l = (unsigned char*)(ws + 1 * MB);      // 1 MB
  float* sB     = (float*)(ws + 2 * MB);                    // 4 KB
  float* sA     = (float*)(ws + 2 * MB + 65536);            // 256 KB
  float* Vb     = (float*)(ws + 2 * MB + 393216);           // 128 KB
  float* e_part = (float*)(ws + 4 * MB);                    // 2 MB
  float* a      = (float*)(ws + 6 * MB);                    // 256 KB
  unsigned char* Kq_h = (unsigned char*)(ws + 8 * MB);      // 64 MB
  unsigned char* Kq_l = (unsigned char*)(ws + 72 * MB);     // 64 MB
  float* part   = e_part;  // aliased: e_part dead after softmax

  quant_kernel<<<256,   256, 0, stream>>>(We,   Wq_h, Wq_l, sB);
  quant_kernel<<<16384, 256, 0, stream>>>(keys, Kq_h, Kq_l, sA);
  v_kernel<<<(NB * NA) / 4, 256, 0, stream>>>(q, Wd, Vb);
  score_i8_kernel<<<4096, 512, 0, stream>>>(Kq_h, Kq_l, Wq_h, Wq_l,
                                            sA, sB, Vb, vw, e_part);
  softmax_kernel<<<NB, 256, 0, stream>>>(e_part, a);
  ctx_partial_i8_kernel<<<NB * 8, 256, 0, stream>>>(a, Kq_h, sA, part);
  ctx_reduce_kernel<<<NB, 256, 0, stream>>>(part, out);
}

// Round 19
// 309.702 us; speedup vs baseline: 1.2367x; 1.0850x over previous
//
#include <hip/hip_runtime.h>
#include <stdint.h>

#define NB 32
#define NS 2048
#define NE 1024   // ENC
#define ND 1024   // DEC
#define NA 1024   // ATT
#define MROWS (NB * NS)   // 65536

typedef float f32x4 __attribute__((ext_vector_type(4)));
typedef int i32x4 __attribute__((ext_vector_type(4)));

typedef __attribute__((address_space(3))) unsigned int lds_u32;
typedef __attribute__((address_space(1))) unsigned int glb_u32;

__device__ __forceinline__ float tanh_fast(float x){
  float ax = fabsf(x);
  float e = __expf(-2.0f * ax);
  float t = (1.0f - e) * __builtin_amdgcn_rcpf(1.0f + e);
  return x < 0.0f ? -t : t;
}
__device__ __forceinline__ void gload_lds16(const void* g, void* l){
  __builtin_amdgcn_global_load_lds((const glb_u32*)g, (lds_u32*)l, 16, 0, 0);
}

#define VMCNT0()  asm volatile("s_waitcnt vmcnt(0)" ::: "memory")

// ---- kernel 0: per-row i8-pair quantize into swizzled group images ---------
// x = s*(h + l/256), s = rowmax/126. Image layout per 256-row mtile (256 KB):
// 16 group-images (16 KB = K=64 x 256 rows); row pair rp = r>>1, c = r&1,
// granule = (c<<2)|(kb ^ (rp&3)), kb = k-block-of-16 within group. Both A and
// B use this identical lane->k packing, so any internal MFMA k-permutation
// cancels. 2-way bank aliasing max (free). Staging stays linear (rule #21).
__global__ __launch_bounds__(256) void quant_kernel(
    const float* __restrict__ src, unsigned char* __restrict__ dh,
    unsigned char* __restrict__ dl, float* __restrict__ sdst)
{
  const int t = threadIdx.x;
  const int w = t >> 6, l = t & 63;
  const int row = blockIdx.x * 4 + w;
  const float* sp = src + (size_t)row * 1024;

  f32x4 x[4];
  #pragma unroll
  for (int c = 0; c < 4; ++c)
    x[c] = *reinterpret_cast<const f32x4*>(sp + c * 256 + l * 4);

  float m = 0.0f;
  #pragma unroll
  for (int c = 0; c < 4; ++c)
    #pragma unroll
    for (int j = 0; j < 4; ++j) m = fmaxf(m, fabsf(x[c][j]));
  #pragma unroll
  for (int off = 1; off < 64; off <<= 1) m = fmaxf(m, __shfl_xor(m, off, 64));
  m = fmaxf(m, 1e-30f);
  const float s = m * (1.0f / 126.0f);
  const float inv = 126.0f / m;

  const int r = row & 255;
  const int rp = r >> 1, cc = r & 1;
  const int kb = (l >> 2) & 3;
  const int gran = (cc << 2) | (kb ^ (rp & 3));
  const size_t base = ((size_t)(row >> 8) << 18) + ((size_t)rp << 7)
                    + ((size_t)gran << 4) + ((l & 3) << 2);

  #pragma unroll
  for (int c = 0; c < 4; ++c){
    int hw = 0, lw = 0;
    #pragma unroll
    for (int j = 0; j < 4; ++j){
      float f = x[c][j] * inv;
      float hf = rintf(f);
      float lf = fminf(rintf((f - hf) * 256.0f), 127.0f);
      hw |= (((int)hf) & 255) << (8 * j);
      lw |= (((int)lf) & 255) << (8 * j);
    }
    const int g = c * 4 + (l >> 4);
    *reinterpret_cast<int*>(dh + base + ((size_t)g << 14)) = hw;
    *reinterpret_cast<int*>(dl + base + ((size_t)g << 14)) = lw;
  }
  if (l == 0) sdst[row] = s;
}

// ---- kernel 1: V[b][a] = sum_d q[b][d]*W_d2a[a][d] -------------------------
__global__ __launch_bounds__(256) void v_kernel(
    const float* __restrict__ q, const float* __restrict__ Wd,
    float* __restrict__ V)
{
  int gw = blockIdx.x * 4 + (threadIdx.x >> 6);
  int l = threadIdx.x & 63;
  int b = gw >> 10, a = gw & 1023;
  const float* qp = q + b * ND;
  const float* wp = Wd + (size_t)a * ND;
  float s = 0.0f;
  #pragma unroll
  for (int c = 0; c < 4; ++c){
    int off = c * 256 + l * 4;
    f32x4 q4 = *reinterpret_cast<const f32x4*>(qp + off);
    f32x4 w4 = *reinterpret_cast<const f32x4*>(wp + off);
    s += q4[0]*w4[0] + q4[1]*w4[1] + q4[2]*w4[2] + q4[3]*w4[3];
  }
  #pragma unroll
  for (int off = 1; off < 64; off <<= 1) s += __shfl_xor(s, off, 64);
  if (l == 0) V[gw] = s;
}

// ---- kernel 2: i8-pair GEMM, wave-private LDS, BARRIER-FREE K-loop ---------
// R12 verbatim (best measured: 205us, MfmaUtil 47%, zero spills/conflicts).
// 128x128 tile, 4 waves (2M x 2N), per-wave 64x64, 2 blocks/CU (66 KB LDS).
// Each wave stages ITS OWN 64-row A-slice into a wave-private double-buffered
// LDS region and reads only what it wrote -> zero barriers in the K-loop.
// Per-group sync is one per-wave vmcnt(0) at group top (drains ops issued a
// whole group earlier, ~free). Bh reg-double-buffered one group ahead from
// the L2-resident W images; Bl loaded at group top, consumed 2 clusters on.
__global__ __launch_bounds__(256, 2) void score_i8_kernel(
    const unsigned char* __restrict__ Kq_h,
    const unsigned char* __restrict__ Kq_l,
    const unsigned char* __restrict__ Wq_h,
    const unsigned char* __restrict__ Wq_l,
    const float* __restrict__ sA, const float* __restrict__ sB,
    const float* __restrict__ Vb, const float* __restrict__ vw,
    float* __restrict__ e_part)
{
  __shared__ __align__(16) unsigned char shb[65536];  // 4 waves x 2 bufs x 8 KB
  __shared__ float ebuf[2][128];
  __shared__ float sAl[128];
  __shared__ float sBl[128];

  const int t = threadIdx.x;
  const int w = t >> 6, l = t & 63;
  const int l15 = l & 15, lg = l >> 4;
  const int wr = w >> 1, wc = w & 1;

  // XCD-bijective swizzle: 8 N-chunks of one M-tile land on one XCD.
  const int orig = blockIdx.x;                 // 0..4095
  const int xcd = orig & 7;
  const int s0 = orig >> 3;
  const int nchunk = s0 & 7;
  const int mtile = ((s0 >> 3) << 3) | xcd;    // [0,512)
  const int row0 = mtile << 7;                 // 128 rows
  const int nb0 = nchunk << 7;
  const int bb = row0 >> 11;

  // A source: 256-row image base + 8KB tile-half + this wave's 4KB row-slice
  const size_t aoff_src = ((size_t)(mtile >> 1) << 18)
                        + ((size_t)(mtile & 1) << 13) + ((size_t)wr << 12);
  const unsigned char* Asrc_h = Kq_h + aoff_src;
  const unsigned char* Asrc_l = Kq_l + aoff_src;
  const size_t boff_src = ((size_t)(nchunk >> 1) << 18) + ((size_t)(nchunk & 1) << 13);

  // frag offsets (16 B each; +1024 per mf/nf step)
  const int swzg = ((((l15 & 1) << 2) | (lg ^ ((l15 >> 1) & 3)))) << 4;
  const int aloc0 = ((l15 >> 1) << 7) + swzg;               // wave-local A
  const int boff0 = (wc << 12) + ((l15 >> 1) << 7) + swzg;  // global B
  const int stl = l << 4;                                   // lane*16

  // wave-private LDS base: 16 KB per wave; buf b at + b*8KB; h [0,4K) l [4K,8K)
  const int wbase = w << 14;

  // per-lane global B bases (L2-resident)
  const unsigned char* pBh = Wq_h + boff_src + boff0;
  const unsigned char* pBl = Wq_l + boff_src + boff0;

  i32x4 acc1[4][4], acc2[4][4];
  #pragma unroll
  for (int mf = 0; mf < 4; ++mf)
    #pragma unroll
    for (int nf = 0; nf < 4; ++nf){ acc1[mf][nf] = (i32x4)0; acc2[mf][nf] = (i32x4)0; }

  // stage this wave's A slice for group g into private buffer buf
  auto stageA = [&](int g, int buf){
    const size_t gb = (size_t)g << 14;
    unsigned char* d = shb + wbase + (buf << 13);
    #pragma unroll
    for (int i = 0; i < 4; ++i){
      gload_lds16(Asrc_h + gb + (i << 10) + stl, d + (i << 10) + stl);
      gload_lds16(Asrc_l + gb + (i << 10) + stl, d + 4096 + (i << 10) + stl);
    }
  };

  i32x4 BhA[4], BhB[4];

  // prologue: B-h(0) -> regs, stage A(0) -> buf0, scales -> LDS
  #pragma unroll
  for (int nf = 0; nf < 4; ++nf)
    BhA[nf] = *reinterpret_cast<const i32x4*>(pBh + nf * 1024);
  stageA(0, 0);
  if (t < 128){ sAl[t] = sA[row0 + t]; sBl[t] = sB[nb0 + t]; }
  __syncthreads();   // guards sAl/sBl for the epilogue; K-loop needs no barrier

  // body: one K=64 group, fully wave-local.
  auto body = [&](int g, i32x4 (&Bhcur)[4], i32x4 (&Bhnext)[4]){
    // drain stage(g)+B(g) — issued one whole group ago, so this is ~free
    VMCNT0();
    const int buf = g & 1;
    const unsigned char* base = shb + wbase + (buf << 13);

    // issue next-group prefetch + this-group B-l up front
    if (g < 15){
      const size_t gb1 = (size_t)(g + 1) << 14;
      #pragma unroll
      for (int nf = 0; nf < 4; ++nf)
        Bhnext[nf] = *reinterpret_cast<const i32x4*>(pBh + gb1 + nf * 1024);
      stageA(g + 1, buf ^ 1);
    }
    i32x4 Bl[4];
    {
      const size_t gb = (size_t)g << 14;
      #pragma unroll
      for (int nf = 0; nf < 4; ++nf)
        Bl[nf] = *reinterpret_cast<const i32x4*>(pBl + gb + nf * 1024);
    }

    // cluster 1: Ah x Bh -> acc1
    i32x4 Ah[4];
    #pragma unroll
    for (int mf = 0; mf < 4; ++mf)
      Ah[mf] = *reinterpret_cast<const i32x4*>(base + aloc0 + mf * 1024);
    __builtin_amdgcn_s_setprio(1);
    #pragma unroll
    for (int nf = 0; nf < 4; ++nf)
      #pragma unroll
      for (int mf = 0; mf < 4; ++mf)
        acc1[mf][nf] = __builtin_amdgcn_mfma_i32_16x16x64_i8(Ah[mf], Bhcur[nf], acc1[mf][nf], 0, 0, 0);
    __builtin_amdgcn_s_setprio(0);

    // cluster 2: Al x Bh -> acc2
    i32x4 Al[4];
    #pragma unroll
    for (int mf = 0; mf < 4; ++mf)
      Al[mf] = *reinterpret_cast<const i32x4*>(base + 4096 + aloc0 + mf * 1024);
    __builtin_amdgcn_s_setprio(1);
    #pragma unroll
    for (int nf = 0; nf < 4; ++nf)
      #pragma unroll
      for (int mf = 0; mf < 4; ++mf)
        acc2[mf][nf] = __builtin_amdgcn_mfma_i32_16x16x64_i8(Al[mf], Bhcur[nf], acc2[mf][nf], 0, 0, 0);
    __builtin_amdgcn_s_setprio(0);

    // cluster 3: Ah x Bl -> acc2 (Bl issued ~2 clusters ago; auto-waited)
    __builtin_amdgcn_s_setprio(1);
    #pragma unroll
    for (int nf = 0; nf < 4; ++nf)
      #pragma unroll
      for (int mf = 0; mf < 4; ++mf)
        acc2[mf][nf] = __builtin_amdgcn_mfma_i32_16x16x64_i8(Ah[mf], Bl[nf], acc2[mf][nf], 0, 0, 0);
    __builtin_amdgcn_s_setprio(0);
  };

  #pragma unroll 1
  for (int gp = 0; gp < 8; ++gp){
    body(2 * gp,     BhA, BhB);
    body(2 * gp + 1, BhB, BhA);
  }

  // epilogue: U = sa*sb*(acc1 + acc2/256); partial e over 128 N-cols
  float sav[16];
  #pragma unroll
  for (int mf = 0; mf < 4; ++mf)
    #pragma unroll
    for (int i = 0; i < 4; ++i)
      sav[(mf << 2) + i] = sAl[(wr << 6) + (mf << 4) + (lg << 2) + i];

  float er[16];
  #pragma unroll
  for (int j = 0; j < 16; ++j) er[j] = 0.0f;
  #pragma unroll
  for (int nf = 0; nf < 4; ++nf){
    const int nl = (wc << 6) + (nf << 4) + l15;
    const int n = nb0 + nl;
    const float sb = sBl[nl];
    const float Vl = Vb[bb * NA + n];
    const float vwl = vw[n];
    #pragma unroll
    for (int mf = 0; mf < 4; ++mf)
      #pragma unroll
      for (int i = 0; i < 4; ++i){
        float U = sav[(mf << 2) + i] * sb *
                  ((float)acc1[mf][nf][i] + (float)acc2[mf][nf][i] * 0.00390625f);
        er[(mf << 2) + i] += tanh_fast(U + Vl) * vwl;
      }
  }
  #pragma unroll
  for (int j = 0; j < 16; ++j){
    #pragma unroll
    for (int off = 1; off < 16; off <<= 1)
      er[j] += __shfl_xor(er[j], off, 64);
  }
  if (l15 == 0){
    #pragma unroll
    for (int mf = 0; mf < 4; ++mf)
      #pragma unroll
      for (int i = 0; i < 4; ++i)
        ebuf[wc][(wr << 6) + (mf << 4) + (lg << 2) + i] = er[(mf << 2) + i];
  }
  __syncthreads();
  if (t < 128)
    e_part[(size_t)nchunk * MROWS + row0 + t] = ebuf[0][t] + ebuf[1][t];
}

// ---- kernel 3: sum 8 partials + softmax over S ------------------------------
__global__ __launch_bounds__(256) void softmax_kernel(
    const float* __restrict__ e_part, float* __restrict__ a)
{
  __shared__ float red[4];
  const int b = blockIdx.x;
  const int t = threadIdx.x;
  const int l = t & 63, w = t >> 6;
  const float* ep = e_part + b * NS + t * 8;
  float v[8];
  #pragma unroll
  for (int j = 0; j < 8; ++j) v[j] = 0.0f;
  #pragma unroll
  for (int c = 0; c < 8; ++c){
    f32x4 x0 = *reinterpret_cast<const f32x4*>(ep + (size_t)c * MROWS);
    f32x4 x1 = *reinterpret_cast<const f32x4*>(ep + (size_t)c * MROWS + 4);
    #pragma unroll
    for (int j = 0; j < 4; ++j){ v[j] += x0[j]; v[4 + j] += x1[j]; }
  }

  float m = v[0];
  #pragma unroll
  for (int j = 1; j < 8; ++j) m = fmaxf(m, v[j]);
  #pragma unroll
  for (int off = 1; off < 64; off <<= 1) m = fmaxf(m, __shfl_xor(m, off, 64));
  if (l == 0) red[w] = m;
  __syncthreads();
  m = fmaxf(fmaxf(red[0], red[1]), fmaxf(red[2], red[3]));
  __syncthreads();

  float ex[8];
  float ssum = 0.0f;
  #pragma unroll
  for (int j = 0; j < 8; ++j){ ex[j] = __expf(v[j] - m); ssum += ex[j]; }
  #pragma unroll
  for (int off = 1; off < 64; off <<= 1) ssum += __shfl_xor(ssum, off, 64);
  if (l == 0) red[w] = ssum;
  __syncthreads();
  ssum = red[0] + red[1] + red[2] + red[3];
  float inv = 1.0f / ssum;

  float o[8];
  #pragma unroll
  for (int j = 0; j < 8; ++j) o[j] = ex[j] * inv;
  float* ap = a + b * NS + t * 8;
  *reinterpret_cast<f32x4*>(ap)     = *reinterpret_cast<f32x4*>(&o[0]);
  *reinterpret_cast<f32x4*>(ap + 4) = *reinterpret_cast<f32x4*>(&o[4]);
}

// ---- kernel 4a: partial context, h-only dequant (R18-verified) -------------
__global__ __launch_bounds__(256) void ctx_partial_i8_kernel(
    const float* __restrict__ a, const unsigned char* __restrict__ Kq_h,
    const float* __restrict__ sA, float* __restrict__ part)
{
  const int bid = blockIdx.x;            // mtile 0..255 = b*8+sc
  const int t = threadIdx.x;             // covers e-cols [4t, 4t+4)
  const int g = t >> 4;
  const int kb = (t >> 2) & 3;
  const size_t ibase = ((size_t)bid << 18) + ((size_t)g << 14) + ((size_t)(t & 3) << 2);
  const float* ap = a + bid * 256;
  const float* sp = sA + bid * 256;
  f32x4 accv = (f32x4)0.0f;
  for (int si = 0; si < 256; ++si){
    const int rp = si >> 1, cc = si & 1;
    const size_t addr = ibase + ((size_t)rp << 7)
                      + ((size_t)(((cc << 2) | (kb ^ (rp & 3))) << 4));
    const int h32 = *reinterpret_cast<const int*>(Kq_h + addr);
    const float t1 = ap[si] * sp[si];
    #pragma unroll
    for (int j = 0; j < 4; ++j){
      int hj = (h32 << ((3 - j) * 8)) >> 24;
      accv[j] += t1 * (float)hj;
    }
  }
  *reinterpret_cast<f32x4*>(part + (size_t)bid * NE + t * 4) = accv;
}

// ---- kernel 4b: deterministic reduce of partials ----------------------------
__global__ __launch_bounds__(256) void ctx_reduce_kernel(
    const float* __restrict__ part, float* __restrict__ out)
{
  const int b = blockIdx.x;
  const int t = threadIdx.x;
  f32x4 s = (f32x4)0.0f;
  #pragma unroll
  for (int sc = 0; sc < 8; ++sc)
    s += *reinterpret_cast<const f32x4*>(part + (size_t)((b << 3) + sc) * NE + t * 4);
  *reinterpret_cast<f32x4*>(out + b * NE + t * 4) = s;
}

extern "C" void kernel_launch(void* const* d_in, const int* in_sizes, int n_in,
                              void* d_out, int out_size, void* d_ws, size_t ws_size,
                              hipStream_t stream)
{
  const float* keys = (const float*)d_in[0];
  const float* q    = (const float*)d_in[1];
  const float* We   = (const float*)d_in[2];
  const float* Wd   = (const float*)d_in[3];
  const float* vw   = (const float*)d_in[4];
  float* out = (float*)d_out;

  char* ws = (char*)d_ws;
  const size_t MB = 1024 * 1024;
  unsigned char* Wq_h = (unsigned char*)(ws);               // 1 MB
  unsigned char* Wq_l = (unsigned char*)(ws + 1 * MB);      // 1 MB
  float* sB     = (float*)(ws + 2 * MB);                    // 4 KB
  float* sA     = (float*)(ws + 2 * MB + 65536);            // 256 KB
  float* Vb     = (float*)(ws + 2 * MB + 393216);           // 128 KB
  float* e_part = (float*)(ws + 4 * MB);                    // 2 MB
  float* a      = (float*)(ws + 6 * MB);                    // 256 KB
  unsigned char* Kq_h = (unsigned char*)(ws + 8 * MB);      // 64 MB
  unsigned char* Kq_l = (unsigned char*)(ws + 72 * MB);     // 64 MB
  float* part   = e_part;  // aliased: e_part dead after softmax

  quant_kernel<<<256,   256, 0, stream>>>(We,   Wq_h, Wq_l, sB);
  quant_kernel<<<16384, 256, 0, stream>>>(keys, Kq_h, Kq_l, sA);
  v_kernel<<<(NB * NA) / 4, 256, 0, stream>>>(q, Wd, Vb);
  score_i8_kernel<<<4096, 256, 0, stream>>>(Kq_h, Kq_l, Wq_h, Wq_l,
                                            sA, sB, Vb, vw, e_part);
  softmax_kernel<<<NB, 256, 0, stream>>>(e_part, a);
  ctx_partial_i8_kernel<<<NB * 8, 256, 0, stream>>>(a, Kq_h, sA, part);
  ctx_reduce_kernel<<<NB, 256, 0, stream>>>(part, out);
}

// Round 20
// 309.333 us; speedup vs baseline: 1.2382x; 1.0012x over previous
//
#include <hip/hip_runtime.h>
#include <stdint.h>

#define NB 32
#define NS 2048
#define NE 1024   // ENC
#define ND 1024   // DEC
#define NA 1024   // ATT
#define MROWS (NB * NS)   // 65536

typedef float f32x4 __attribute__((ext_vector_type(4)));
typedef int i32x4 __attribute__((ext_vector_type(4)));

typedef __attribute__((address_space(3))) unsigned int lds_u32;
typedef __attribute__((address_space(1))) unsigned int glb_u32;

__device__ __forceinline__ float tanh_fast(float x){
  float ax = fabsf(x);
  float e = __expf(-2.0f * ax);
  float t = (1.0f - e) * __builtin_amdgcn_rcpf(1.0f + e);
  return x < 0.0f ? -t : t;
}
__device__ __forceinline__ void gload_lds16(const void* g, void* l){
  __builtin_amdgcn_global_load_lds((const glb_u32*)g, (lds_u32*)l, 16, 0, 0);
}

#define VMCNT0()  asm volatile("s_waitcnt vmcnt(0)" ::: "memory")

// ---- kernel 0: per-row i8-pair quantize into swizzled group images ---------
// x = s*(h + l/256), s = rowmax/126. Image layout per 256-row mtile (256 KB):
// 16 group-images (16 KB = K=64 x 256 rows); row pair rp = r>>1, c = r&1,
// granule = (c<<2)|(kb ^ (rp&3)), kb = k-block-of-16 within group. Both A and
// B use this identical lane->k packing, so any internal MFMA k-permutation
// cancels. 2-way bank aliasing max (free). Staging stays linear (rule #21).
__global__ __launch_bounds__(256) void quant_kernel(
    const float* __restrict__ src, unsigned char* __restrict__ dh,
    unsigned char* __restrict__ dl, float* __restrict__ sdst)
{
  const int t = threadIdx.x;
  const int w = t >> 6, l = t & 63;
  const int row = blockIdx.x * 4 + w;
  const float* sp = src + (size_t)row * 1024;

  f32x4 x[4];
  #pragma unroll
  for (int c = 0; c < 4; ++c)
    x[c] = *reinterpret_cast<const f32x4*>(sp + c * 256 + l * 4);

  float m = 0.0f;
  #pragma unroll
  for (int c = 0; c < 4; ++c)
    #pragma unroll
    for (int j = 0; j < 4; ++j) m = fmaxf(m, fabsf(x[c][j]));
  #pragma unroll
  for (int off = 1; off < 64; off <<= 1) m = fmaxf(m, __shfl_xor(m, off, 64));
  m = fmaxf(m, 1e-30f);
  const float s = m * (1.0f / 126.0f);
  const float inv = 126.0f / m;

  const int r = row & 255;
  const int rp = r >> 1, cc = r & 1;
  const int kb = (l >> 2) & 3;
  const int gran = (cc << 2) | (kb ^ (rp & 3));
  const size_t base = ((size_t)(row >> 8) << 18) + ((size_t)rp << 7)
                    + ((size_t)gran << 4) + ((l & 3) << 2);

  #pragma unroll
  for (int c = 0; c < 4; ++c){
    int hw = 0, lw = 0;
    #pragma unroll
    for (int j = 0; j < 4; ++j){
      float f = x[c][j] * inv;
      float hf = rintf(f);
      float lf = fminf(rintf((f - hf) * 256.0f), 127.0f);
      hw |= (((int)hf) & 255) << (8 * j);
      lw |= (((int)lf) & 255) << (8 * j);
    }
    const int g = c * 4 + (l >> 4);
    *reinterpret_cast<int*>(dh + base + ((size_t)g << 14)) = hw;
    *reinterpret_cast<int*>(dl + base + ((size_t)g << 14)) = lw;
  }
  if (l == 0) sdst[row] = s;
}

// ---- kernel 1: V[b][a] = sum_d q[b][d]*W_d2a[a][d] -------------------------
__global__ __launch_bounds__(256) void v_kernel(
    const float* __restrict__ q, const float* __restrict__ Wd,
    float* __restrict__ V)
{
  int gw = blockIdx.x * 4 + (threadIdx.x >> 6);
  int l = threadIdx.x & 63;
  int b = gw >> 10, a = gw & 1023;
  const float* qp = q + b * ND;
  const float* wp = Wd + (size_t)a * ND;
  float s = 0.0f;
  #pragma unroll
  for (int c = 0; c < 4; ++c){
    int off = c * 256 + l * 4;
    f32x4 q4 = *reinterpret_cast<const f32x4*>(qp + off);
    f32x4 w4 = *reinterpret_cast<const f32x4*>(wp + off);
    s += q4[0]*w4[0] + q4[1]*w4[1] + q4[2]*w4[2] + q4[3]*w4[3];
  }
  #pragma unroll
  for (int off = 1; off < 64; off <<= 1) s += __shfl_xor(s, off, 64);
  if (l == 0) V[gw] = s;
}

// ---- kernel 2: i8-pair GEMM, wave-private LDS, BARRIER-FREE K-loop ---------
// R12 verbatim (best measured: 205us, MfmaUtil 47%, zero spills/conflicts).
// 128x128 tile, 4 waves (2M x 2N), per-wave 64x64, 2 blocks/CU (66 KB LDS).
// Each wave stages ITS OWN 64-row A-slice into a wave-private double-buffered
// LDS region and reads only what it wrote -> zero barriers in the K-loop.
// Per-group sync is one per-wave vmcnt(0) at group top (drains ops issued a
// whole group earlier, ~free). Bh reg-double-buffered one group ahead from
// the L2-resident W images; Bl loaded at group top, consumed 2 clusters on.
__global__ __launch_bounds__(256, 2) void score_i8_kernel(
    const unsigned char* __restrict__ Kq_h,
    const unsigned char* __restrict__ Kq_l,
    const unsigned char* __restrict__ Wq_h,
    const unsigned char* __restrict__ Wq_l,
    const float* __restrict__ sA, const float* __restrict__ sB,
    const float* __restrict__ Vb, const float* __restrict__ vw,
    float* __restrict__ e_part)
{
  __shared__ __align__(16) unsigned char shb[65536];  // 4 waves x 2 bufs x 8 KB
  __shared__ float ebuf[2][128];
  __shared__ float sAl[128];
  __shared__ float sBl[128];

  const int t = threadIdx.x;
  const int w = t >> 6, l = t & 63;
  const int l15 = l & 15, lg = l >> 4;
  const int wr = w >> 1, wc = w & 1;

  // XCD-bijective swizzle: 8 N-chunks of one M-tile land on one XCD.
  const int orig = blockIdx.x;                 // 0..4095
  const int xcd = orig & 7;
  const int s0 = orig >> 3;
  const int nchunk = s0 & 7;
  const int mtile = ((s0 >> 3) << 3) | xcd;    // [0,512)
  const int row0 = mtile << 7;                 // 128 rows
  const int nb0 = nchunk << 7;
  const int bb = row0 >> 11;

  // A source: 256-row image base + 8KB tile-half + this wave's 4KB row-slice
  const size_t aoff_src = ((size_t)(mtile >> 1) << 18)
                        + ((size_t)(mtile & 1) << 13) + ((size_t)wr << 12);
  const unsigned char* Asrc_h = Kq_h + aoff_src;
  const unsigned char* Asrc_l = Kq_l + aoff_src;
  const size_t boff_src = ((size_t)(nchunk >> 1) << 18) + ((size_t)(nchunk & 1) << 13);

  // frag offsets (16 B each; +1024 per mf/nf step)
  const int swzg = ((((l15 & 1) << 2) | (lg ^ ((l15 >> 1) & 3)))) << 4;
  const int aloc0 = ((l15 >> 1) << 7) + swzg;               // wave-local A
  const int boff0 = (wc << 12) + ((l15 >> 1) << 7) + swzg;  // global B
  const int stl = l << 4;                                   // lane*16

  // wave-private LDS base: 16 KB per wave; buf b at + b*8KB; h [0,4K) l [4K,8K)
  const int wbase = w << 14;

  // per-lane global B bases (L2-resident)
  const unsigned char* pBh = Wq_h + boff_src + boff0;
  const unsigned char* pBl = Wq_l + boff_src + boff0;

  i32x4 acc1[4][4], acc2[4][4];
  #pragma unroll
  for (int mf = 0; mf < 4; ++mf)
    #pragma unroll
    for (int nf = 0; nf < 4; ++nf){ acc1[mf][nf] = (i32x4)0; acc2[mf][nf] = (i32x4)0; }

  // stage this wave's A slice for group g into private buffer buf
  auto stageA = [&](int g, int buf){
    const size_t gb = (size_t)g << 14;
    unsigned char* d = shb + wbase + (buf << 13);
    #pragma unroll
    for (int i = 0; i < 4; ++i){
      gload_lds16(Asrc_h + gb + (i << 10) + stl, d + (i << 10) + stl);
      gload_lds16(Asrc_l + gb + (i << 10) + stl, d + 4096 + (i << 10) + stl);
    }
  };

  i32x4 BhA[4], BhB[4];

  // prologue: B-h(0) -> regs, stage A(0) -> buf0, scales -> LDS
  #pragma unroll
  for (int nf = 0; nf < 4; ++nf)
    BhA[nf] = *reinterpret_cast<const i32x4*>(pBh + nf * 1024);
  stageA(0, 0);
  if (t < 128){ sAl[t] = sA[row0 + t]; sBl[t] = sB[nb0 + t]; }
  __syncthreads();   // guards sAl/sBl for the epilogue; K-loop needs no barrier

  // body: one K=64 group, fully wave-local.
  auto body = [&](int g, i32x4 (&Bhcur)[4], i32x4 (&Bhnext)[4]){
    // drain stage(g)+B(g) — issued one whole group ago, so this is ~free
    VMCNT0();
    const int buf = g & 1;
    const unsigned char* base = shb + wbase + (buf << 13);

    // issue next-group prefetch + this-group B-l up front
    if (g < 15){
      const size_t gb1 = (size_t)(g + 1) << 14;
      #pragma unroll
      for (int nf = 0; nf < 4; ++nf)
        Bhnext[nf] = *reinterpret_cast<const i32x4*>(pBh + gb1 + nf * 1024);
      stageA(g + 1, buf ^ 1);
    }
    i32x4 Bl[4];
    {
      const size_t gb = (size_t)g << 14;
      #pragma unroll
      for (int nf = 0; nf < 4; ++nf)
        Bl[nf] = *reinterpret_cast<const i32x4*>(pBl + gb + nf * 1024);
    }

    // cluster 1: Ah x Bh -> acc1
    i32x4 Ah[4];
    #pragma unroll
    for (int mf = 0; mf < 4; ++mf)
      Ah[mf] = *reinterpret_cast<const i32x4*>(base + aloc0 + mf * 1024);
    __builtin_amdgcn_s_setprio(1);
    #pragma unroll
    for (int nf = 0; nf < 4; ++nf)
      #pragma unroll
      for (int mf = 0; mf < 4; ++mf)
        acc1[mf][nf] = __builtin_amdgcn_mfma_i32_16x16x64_i8(Ah[mf], Bhcur[nf], acc1[mf][nf], 0, 0, 0);
    __builtin_amdgcn_s_setprio(0);

    // cluster 2: Al x Bh -> acc2
    i32x4 Al[4];
    #pragma unroll
    for (int mf = 0; mf < 4; ++mf)
      Al[mf] = *reinterpret_cast<const i32x4*>(base + 4096 + aloc0 + mf * 1024);
    __builtin_amdgcn_s_setprio(1);
    #pragma unroll
    for (int nf = 0; nf < 4; ++nf)
      #pragma unroll
      for (int mf = 0; mf < 4; ++mf)
        acc2[mf][nf] = __builtin_amdgcn_mfma_i32_16x16x64_i8(Al[mf], Bhcur[nf], acc2[mf][nf], 0, 0, 0);
    __builtin_amdgcn_s_setprio(0);

    // cluster 3: Ah x Bl -> acc2 (Bl issued ~2 clusters ago; auto-waited)
    __builtin_amdgcn_s_setprio(1);
    #pragma unroll
    for (int nf = 0; nf < 4; ++nf)
      #pragma unroll
      for (int mf = 0; mf < 4; ++mf)
        acc2[mf][nf] = __builtin_amdgcn_mfma_i32_16x16x64_i8(Ah[mf], Bl[nf], acc2[mf][nf], 0, 0, 0);
    __builtin_amdgcn_s_setprio(0);
  };

  #pragma unroll 1
  for (int gp = 0; gp < 8; ++gp){
    body(2 * gp,     BhA, BhB);
    body(2 * gp + 1, BhB, BhA);
  }

  // epilogue: U = sa*sb*(acc1 + acc2/256); partial e over 128 N-cols
  float sav[16];
  #pragma unroll
  for (int mf = 0; mf < 4; ++mf)
    #pragma unroll
    for (int i = 0; i < 4; ++i)
      sav[(mf << 2) + i] = sAl[(wr << 6) + (mf << 4) + (lg << 2) + i];

  float er[16];
  #pragma unroll
  for (int j = 0; j < 16; ++j) er[j] = 0.0f;
  #pragma unroll
  for (int nf = 0; nf < 4; ++nf){
    const int nl = (wc << 6) + (nf << 4) + l15;
    const int n = nb0 + nl;
    const float sb = sBl[nl];
    const float Vl = Vb[bb * NA + n];
    const float vwl = vw[n];
    #pragma unroll
    for (int mf = 0; mf < 4; ++mf)
      #pragma unroll
      for (int i = 0; i < 4; ++i){
        float U = sav[(mf << 2) + i] * sb *
                  ((float)acc1[mf][nf][i] + (float)acc2[mf][nf][i] * 0.00390625f);
        er[(mf << 2) + i] += tanh_fast(U + Vl) * vwl;
      }
  }
  #pragma unroll
  for (int j = 0; j < 16; ++j){
    #pragma unroll
    for (int off = 1; off < 16; off <<= 1)
      er[j] += __shfl_xor(er[j], off, 64);
  }
  if (l15 == 0){
    #pragma unroll
    for (int mf = 0; mf < 4; ++mf)
      #pragma unroll
      for (int i = 0; i < 4; ++i)
        ebuf[wc][(wr << 6) + (mf << 4) + (lg << 2) + i] = er[(mf << 2) + i];
  }
  __syncthreads();
  if (t < 128)
    e_part[(size_t)nchunk * MROWS + row0 + t] = ebuf[0][t] + ebuf[1][t];
}

// ---- kernel 3: sum 8 partials + softmax over S ------------------------------
__global__ __launch_bounds__(256) void softmax_kernel(
    const float* __restrict__ e_part, float* __restrict__ a)
{
  __shared__ float red[4];
  const int b = blockIdx.x;
  const int t = threadIdx.x;
  const int l = t & 63, w = t >> 6;
  const float* ep = e_part + b * NS + t * 8;
  float v[8];
  #pragma unroll
  for (int j = 0; j < 8; ++j) v[j] = 0.0f;
  #pragma unroll
  for (int c = 0; c < 8; ++c){
    f32x4 x0 = *reinterpret_cast<const f32x4*>(ep + (size_t)c * MROWS);
    f32x4 x1 = *reinterpret_cast<const f32x4*>(ep + (size_t)c * MROWS + 4);
    #pragma unroll
    for (int j = 0; j < 4; ++j){ v[j] += x0[j]; v[4 + j] += x1[j]; }
  }

  float m = v[0];
  #pragma unroll
  for (int j = 1; j < 8; ++j) m = fmaxf(m, v[j]);
  #pragma unroll
  for (int off = 1; off < 64; off <<= 1) m = fmaxf(m, __shfl_xor(m, off, 64));
  if (l == 0) red[w] = m;
  __syncthreads();
  m = fmaxf(fmaxf(red[0], red[1]), fmaxf(red[2], red[3]));
  __syncthreads();

  float ex[8];
  float ssum = 0.0f;
  #pragma unroll
  for (int j = 0; j < 8; ++j){ ex[j] = __expf(v[j] - m); ssum += ex[j]; }
  #pragma unroll
  for (int off = 1; off < 64; off <<= 1) ssum += __shfl_xor(ssum, off, 64);
  if (l == 0) red[w] = ssum;
  __syncthreads();
  ssum = red[0] + red[1] + red[2] + red[3];
  float inv = 1.0f / ssum;

  float o[8];
  #pragma unroll
  for (int j = 0; j < 8; ++j) o[j] = ex[j] * inv;
  float* ap = a + b * NS + t * 8;
  *reinterpret_cast<f32x4*>(ap)     = *reinterpret_cast<f32x4*>(&o[0]);
  *reinterpret_cast<f32x4*>(ap + 4) = *reinterpret_cast<f32x4*>(&o[4]);
}

// ---- kernel 4a: partial context, h-only dequant (R18-verified) -------------
__global__ __launch_bounds__(256) void ctx_partial_i8_kernel(
    const float* __restrict__ a, const unsigned char* __restrict__ Kq_h,
    const float* __restrict__ sA, float* __restrict__ part)
{
  const int bid = blockIdx.x;            // mtile 0..255 = b*8+sc
  const int t = threadIdx.x;             // covers e-cols [4t, 4t+4)
  const int g = t >> 4;
  const int kb = (t >> 2) & 3;
  const size_t ibase = ((size_t)bid << 18) + ((size_t)g << 14) + ((size_t)(t & 3) << 2);
  const float* ap = a + bid * 256;
  const float* sp = sA + bid * 256;
  f32x4 accv = (f32x4)0.0f;
  for (int si = 0; si < 256; ++si){
    const int rp = si >> 1, cc = si & 1;
    const size_t addr = ibase + ((size_t)rp << 7)
                      + ((size_t)(((cc << 2) | (kb ^ (rp & 3))) << 4));
    const int h32 = *reinterpret_cast<const int*>(Kq_h + addr);
    const float t1 = ap[si] * sp[si];
    #pragma unroll
    for (int j = 0; j < 4; ++j){
      int hj = (h32 << ((3 - j) * 8)) >> 24;
      accv[j] += t1 * (float)hj;
    }
  }
  *reinterpret_cast<f32x4*>(part + (size_t)bid * NE + t * 4) = accv;
}

// ---- kernel 4b: deterministic reduce of partials ----------------------------
__global__ __launch_bounds__(256) void ctx_reduce_kernel(
    const float* __restrict__ part, float* __restrict__ out)
{
  const int b = blockIdx.x;
  const int t = threadIdx.x;
  f32x4 s = (f32x4)0.0f;
  #pragma unroll
  for (int sc = 0; sc < 8; ++sc)
    s += *reinterpret_cast<const f32x4*>(part + (size_t)((b << 3) + sc) * NE + t * 4);
  *reinterpret_cast<f32x4*>(out + b * NE + t * 4) = s;
}

extern "C" void kernel_launch(void* const* d_in, const int* in_sizes, int n_in,
                              void* d_out, int out_size, void* d_ws, size_t ws_size,
                              hipStream_t stream)
{
  const float* keys = (const float*)d_in[0];
  const float* q    = (const float*)d_in[1];
  const float* We   = (const float*)d_in[2];
  const float* Wd   = (const float*)d_in[3];
  const float* vw   = (const float*)d_in[4];
  float* out = (float*)d_out;

  char* ws = (char*)d_ws;
  const size_t MB = 1024 * 1024;
  unsigned char* Wq_h = (unsigned char*)(ws);               // 1 MB
  unsigned char* Wq_l = (unsigned char*)(ws + 1 * MB);      // 1 MB
  float* sB     = (float*)(ws + 2 * MB);                    // 4 KB
  float* sA     = (float*)(ws + 2 * MB + 65536);            // 256 KB
  float* Vb     = (float*)(ws + 2 * MB + 393216);           // 128 KB
  float* e_part = (float*)(ws + 4 * MB);                    // 2 MB
  float* a      = (float*)(ws + 6 * MB);                    // 256 KB
  unsigned char* Kq_h = (unsigned char*)(ws + 8 * MB);      // 64 MB
  unsigned char* Kq_l = (unsigned char*)(ws + 72 * MB);     // 64 MB
  float* part   = e_part;  // aliased: e_part dead after softmax

  quant_kernel<<<256,   256, 0, stream>>>(We,   Wq_h, Wq_l, sB);
  quant_kernel<<<16384, 256, 0, stream>>>(keys, Kq_h, Kq_l, sA);
  v_kernel<<<(NB * NA) / 4, 256, 0, stream>>>(q, Wd, Vb);
  score_i8_kernel<<<4096, 256, 0, stream>>>(Kq_h, Kq_l, Wq_h, Wq_l,
                                            sA, sB, Vb, vw, e_part);
  softmax_kernel<<<NB, 256, 0, stream>>>(e_part, a);
  ctx_partial_i8_kernel<<<NB * 8, 256, 0, stream>>>(a, Kq_h, sA, part);
  ctx_reduce_kernel<<<NB, 256, 0, stream>>>(part, out);
}